// Round 6
// baseline (218.760 us; speedup 1.0000x reference)
//
#include <hip/hip_runtime.h>
#include <hip/hip_bf16.h>

// Problem constants (fixed by setup_inputs)
#define N_NODES  50000
#define D_NODE   128
#define E_TOTAL  600000
#define IN_FEAT  256      // 2 * d_node
#define OUT_FEAT 128
#define ALPHA_OFF (600000 * 128)   // fits in int32 (77.4M)

typedef __bf16 bf16x8 __attribute__((ext_vector_type(8)));
typedef float  f32x4  __attribute__((ext_vector_type(4)));

// ================= FAST PATH =================
// sigmoid(W.[nf_src|nf_dst]) = sigmoid(zs[src] + zd[dst]),
//   zs = n_f @ W[:, :128]^T,  zd = n_f @ W[:, 128:]^T  (per-node, reused ~12x/node)
// Z stored bf16 [N_NODES][256] (zs cols 0..127, zd cols 128..255) = 25.6 MB.
// R5: non-temporal stores on the 310 MB output stream so it does not evict Z
// from L2/L3 (Z must stay cache-resident for the random gathers).

// ---- prep: Wcat -> per-fragment-swizzled bf16 (for the node-projection GEMM) ----
// Wcat[o2][k2] = o2<128 ? W[o2][k2] : W[o2-128][128+k2]   (o2<256, k2<128)
// wl[(((kk*16 + n)*64) + lane)*8 + j] = Wcat[n*16 + (lane&15)][kk*32 + (lane>>4)*8 + j]
__global__ void convert_wcat(const float* __restrict__ W, __bf16* __restrict__ wl) {
    int gid  = blockIdx.x * 256 + threadIdx.x;   // 0..4095, one bf16x8 each
    int lane = gid & 63;
    int nk   = gid >> 6;        // 0..63
    int n    = nk & 15;         // 16 col-groups (N=256)
    int kk   = nk >> 4;         // 0..3       (K=128)
    int o2   = n * 16 + (lane & 15);
    int k2   = kk * 32 + (lane >> 4) * 8;
    const float* src = (o2 < 128) ? (W + o2 * IN_FEAT + k2)
                                  : (W + (o2 - 128) * IN_FEAT + 128 + k2);
    bf16x8 h;
    #pragma unroll
    for (int j = 0; j < 8; ++j) h[j] = (__bf16)src[j];
    *(bf16x8*)(wl + gid * 8) = h;
}

// ---- node projection: Z[v][o2] = sum_k n_f[v][k] * Wcat[o2][k] ----
// one wave = 16 nodes x 256 cols, K=128. 50000 = 3125 * 16 exact.
__launch_bounds__(64)
__global__ void zgemm(const float* __restrict__ n_f,
                      const __bf16* __restrict__ wl,
                      __bf16* __restrict__ Z) {
    const int lane = threadIdx.x;
    const int v0   = blockIdx.x * 16;
    const int lr   = lane & 15;
    const int lg   = lane >> 4;

    f32x4 acc[16];
    #pragma unroll
    for (int n = 0; n < 16; ++n) acc[n] = (f32x4){0.f, 0.f, 0.f, 0.f};

    #pragma unroll
    for (int kk = 0; kk < 4; ++kk) {               // K = 128 = 4 * 32
        const float* ap = n_f + (v0 + lr) * D_NODE + kk * 32 + lg * 8;
        float4 v0f = *(const float4*)ap;
        float4 v1f = *(const float4*)(ap + 4);
        bf16x8 a;
        a[0] = (__bf16)v0f.x; a[1] = (__bf16)v0f.y;
        a[2] = (__bf16)v0f.z; a[3] = (__bf16)v0f.w;
        a[4] = (__bf16)v1f.x; a[5] = (__bf16)v1f.y;
        a[6] = (__bf16)v1f.z; a[7] = (__bf16)v1f.w;
        const bf16x8* bp = (const bf16x8*)(wl) + kk * 16 * 64 + lane;
        #pragma unroll
        for (int n = 0; n < 16; ++n) {             // N = 256 = 16 * 16
            bf16x8 b = bp[n * 64];
            acc[n] = __builtin_amdgcn_mfma_f32_16x16x32_bf16(a, b, acc[n], 0, 0, 0);
        }
    }

    // C layout: col = n*16 + (lane&15), row = (lane>>4)*4 + j
    #pragma unroll
    for (int n = 0; n < 16; ++n) {
        const int col = n * 16 + lr;
        #pragma unroll
        for (int j = 0; j < 4; ++j)
            Z[(v0 + lg * 4 + j) * 256 + col] = (__bf16)acc[n][j];
    }
}

// ---- edge apply: out[e][o] = sigmoid( Z[src][o] + Z[dst][128+o] ) ----
// 8 lanes per edge, 16 cols each. 600000 / 32 edges-per-block = 18750 exact.
// Output stores are non-temporal: pure streaming data, must not evict Z.
__launch_bounds__(256)
__global__ void edge_apply(const __bf16* __restrict__ Z,
                           const int* __restrict__ src_idx,
                           const int* __restrict__ dst_idx,
                           float* __restrict__ out) {
    const int e   = blockIdx.x * 32 + (threadIdx.x >> 3);
    const int sub = threadIdx.x & 7;
    const int sv  = __builtin_nontemporal_load(src_idx + e);
    const int dv  = __builtin_nontemporal_load(dst_idx + e);

    if (sub == 0) __builtin_nontemporal_store(1.0f, out + ALPHA_OFF + e);

    const __bf16* zs = Z + sv * 256 + sub * 16;
    const __bf16* zd = Z + dv * 256 + 128 + sub * 16;
    bf16x8 s0 = *(const bf16x8*)(zs);
    bf16x8 s1 = *(const bf16x8*)(zs + 8);
    bf16x8 d0 = *(const bf16x8*)(zd);
    bf16x8 d1 = *(const bf16x8*)(zd + 8);

    float r[16];
    #pragma unroll
    for (int j = 0; j < 8; ++j) {
        float x0 = (float)s0[j] + (float)d0[j];
        float x1 = (float)s1[j] + (float)d1[j];
        r[j]     = __builtin_amdgcn_rcpf(1.0f + __expf(-x0));
        r[8 + j] = __builtin_amdgcn_rcpf(1.0f + __expf(-x1));
    }
    f32x4* o = (f32x4*)(out + e * OUT_FEAT + sub * 16);
    #pragma unroll
    for (int q = 0; q < 4; ++q) {
        f32x4 v = (f32x4){r[q * 4], r[q * 4 + 1], r[q * 4 + 2], r[q * 4 + 3]};
        __builtin_nontemporal_store(v, o + q);
    }
}

// ================= FALLBACK PATH (R3, needs only 64 KB ws) =================
__global__ void convert_w_fb(const float* __restrict__ W, __bf16* __restrict__ wl) {
    int gid = blockIdx.x * 256 + threadIdx.x;
    int lane = gid & 63;
    int nk   = gid >> 6;
    int n    = nk & 7;
    int kk   = nk >> 3;
    int row  = n * 16 + (lane & 15);
    int col  = kk * 32 + (lane >> 4) * 8;
    const float* src = W + row * IN_FEAT + col;
    bf16x8 h;
    #pragma unroll
    for (int j = 0; j < 8; ++j) h[j] = (__bf16)src[j];
    *(bf16x8*)(wl + gid * 8) = h;
}

__launch_bounds__(64, 2)
__global__ void edge_kernel_fb(const float* __restrict__ n_f,
                               const __bf16* __restrict__ wl,
                               const int*   __restrict__ src_idx,
                               const int*   __restrict__ dst_idx,
                               float* __restrict__ out) {
    const int lane = threadIdx.x;
    const int e0   = blockIdx.x * 64;
    const int lr   = lane & 15;
    const int lg   = lane >> 4;

    out[ALPHA_OFF + e0 + lane] = 1.0f;

    int sn[4], dn[4];
    #pragma unroll
    for (int r = 0; r < 4; ++r) {
        const int e = e0 + r * 16 + lr;
        sn[r] = src_idx[e];
        dn[r] = dst_idx[e];
    }
    f32x4 acc[4][8];
    #pragma unroll
    for (int r = 0; r < 4; ++r)
        #pragma unroll
        for (int n = 0; n < 8; ++n) acc[r][n] = (f32x4){0.f, 0.f, 0.f, 0.f};

    #pragma unroll
    for (int kk = 0; kk < 8; ++kk) {
        bf16x8 a[4];
        #pragma unroll
        for (int r = 0; r < 4; ++r) {
            const int node = (kk < 4) ? sn[r] : dn[r];
            const float* ap = n_f + node * D_NODE + (kk & 3) * 32 + lg * 8;
            float4 u0 = *(const float4*)ap;
            float4 u1 = *(const float4*)(ap + 4);
            a[r][0] = (__bf16)u0.x; a[r][1] = (__bf16)u0.y;
            a[r][2] = (__bf16)u0.z; a[r][3] = (__bf16)u0.w;
            a[r][4] = (__bf16)u1.x; a[r][5] = (__bf16)u1.y;
            a[r][6] = (__bf16)u1.z; a[r][7] = (__bf16)u1.w;
        }
        const bf16x8* bp = (const bf16x8*)(wl) + kk * 8 * 64 + lane;
        #pragma unroll
        for (int n = 0; n < 8; ++n) {
            bf16x8 b = bp[n * 64];
            #pragma unroll
            for (int r = 0; r < 4; ++r)
                acc[r][n] = __builtin_amdgcn_mfma_f32_16x16x32_bf16(a[r], b, acc[r][n], 0, 0, 0);
        }
    }
    #pragma unroll
    for (int r = 0; r < 4; ++r) {
        const int ebase = e0 + r * 16 + lg * 4;
        #pragma unroll
        for (int n = 0; n < 8; ++n) {
            const int col = n * 16 + lr;
            #pragma unroll
            for (int j = 0; j < 4; ++j) {
                float x = acc[r][n][j];
                out[(ebase + j) * OUT_FEAT + col] = __builtin_amdgcn_rcpf(1.0f + __expf(-x));
            }
        }
    }
}

extern "C" void kernel_launch(void* const* d_in, const int* in_sizes, int n_in,
                              void* d_out, int out_size, void* d_ws, size_t ws_size,
                              hipStream_t stream) {
    const float* n_f    = (const float*)d_in[0];
    const float* W_edge = (const float*)d_in[1];
    // d_in[2] = W_attn: mathematically dead (softmax over size-1 axis == 1)
    const int* src_idx  = (const int*)d_in[3];
    const int* dst_idx  = (const int*)d_in[4];
    float* out = (float*)d_out;

    const size_t need = 65536 + (size_t)N_NODES * 256 * sizeof(__bf16);  // wl + Z
    if (ws_size >= need) {
        __bf16* wl = (__bf16*)d_ws;                       // 64 KB
        __bf16* Z  = (__bf16*)((char*)d_ws + 65536);      // 25.6 MB
        convert_wcat<<<16, 256, 0, stream>>>(W_edge, wl);
        zgemm<<<N_NODES / 16, 64, 0, stream>>>(n_f, wl, Z);
        edge_apply<<<E_TOTAL / 32, 256, 0, stream>>>(Z, src_idx, dst_idx, out);
    } else {
        __bf16* wl = (__bf16*)d_ws;                       // 64 KB
        convert_w_fb<<<16, 256, 0, stream>>>(W_edge, wl);
        edge_kernel_fb<<<E_TOTAL / 64, 64, 0, stream>>>(n_f, wl, src_idx, dst_idx, out);
    }
}

// Round 7
// 140.841 us; speedup vs baseline: 1.5532x; 1.5532x over previous
//
#include <hip/hip_runtime.h>
#include <hip/hip_bf16.h>

// Problem constants (fixed by setup_inputs)
#define N_NODES  50000
#define D_NODE   128
#define E_TOTAL  600000
#define IN_FEAT  256      // 2 * d_node
#define OUT_FEAT 128
#define ALPHA_OFF (600000 * 128)   // fits in int32 (77.4M)

typedef __bf16 bf16x8 __attribute__((ext_vector_type(8)));
typedef float  f32x4  __attribute__((ext_vector_type(4)));

// ================= FAST PATH =================
// sigmoid(W.[nf_src|nf_dst]) = sigmoid(zs[src] + zd[dst]),
//   zs = n_f @ W[:, :128]^T,  zd = n_f @ W[:, 128:]^T  (per-node, reused ~12x/node)
// Z stored bf16 [N_NODES][256] (zs cols 0..127, zd cols 128..255) = 25.6 MB.
// R6 lesson: nt stores bypass L2 write-combining; 16B partial-line stores then
// amplify HBM writes 1.7x (WRITE_SIZE 302->513 MB). Stores stay normal.
// R7: 2 edges/thread -> 4 independent Z gathers in flight (latency hiding).

// ---- prep: Wcat -> per-fragment-swizzled bf16 (for the node-projection GEMM) ----
// Wcat[o2][k2] = o2<128 ? W[o2][k2] : W[o2-128][128+k2]   (o2<256, k2<128)
// wl[(((kk*16 + n)*64) + lane)*8 + j] = Wcat[n*16 + (lane&15)][kk*32 + (lane>>4)*8 + j]
__global__ void convert_wcat(const float* __restrict__ W, __bf16* __restrict__ wl) {
    int gid  = blockIdx.x * 256 + threadIdx.x;   // 0..4095, one bf16x8 each
    int lane = gid & 63;
    int nk   = gid >> 6;        // 0..63
    int n    = nk & 15;         // 16 col-groups (N=256)
    int kk   = nk >> 4;         // 0..3       (K=128)
    int o2   = n * 16 + (lane & 15);
    int k2   = kk * 32 + (lane >> 4) * 8;
    const float* src = (o2 < 128) ? (W + o2 * IN_FEAT + k2)
                                  : (W + (o2 - 128) * IN_FEAT + 128 + k2);
    bf16x8 h;
    #pragma unroll
    for (int j = 0; j < 8; ++j) h[j] = (__bf16)src[j];
    *(bf16x8*)(wl + gid * 8) = h;
}

// ---- node projection: Z[v][o2] = sum_k n_f[v][k] * Wcat[o2][k] ----
// one wave = 16 nodes x 256 cols, K=128. 50000 = 3125 * 16 exact.
__launch_bounds__(64)
__global__ void zgemm(const float* __restrict__ n_f,
                      const __bf16* __restrict__ wl,
                      __bf16* __restrict__ Z) {
    const int lane = threadIdx.x;
    const int v0   = blockIdx.x * 16;
    const int lr   = lane & 15;
    const int lg   = lane >> 4;

    f32x4 acc[16];
    #pragma unroll
    for (int n = 0; n < 16; ++n) acc[n] = (f32x4){0.f, 0.f, 0.f, 0.f};

    #pragma unroll
    for (int kk = 0; kk < 4; ++kk) {               // K = 128 = 4 * 32
        const float* ap = n_f + (v0 + lr) * D_NODE + kk * 32 + lg * 8;
        float4 v0f = *(const float4*)ap;
        float4 v1f = *(const float4*)(ap + 4);
        bf16x8 a;
        a[0] = (__bf16)v0f.x; a[1] = (__bf16)v0f.y;
        a[2] = (__bf16)v0f.z; a[3] = (__bf16)v0f.w;
        a[4] = (__bf16)v1f.x; a[5] = (__bf16)v1f.y;
        a[6] = (__bf16)v1f.z; a[7] = (__bf16)v1f.w;
        const bf16x8* bp = (const bf16x8*)(wl) + kk * 16 * 64 + lane;
        #pragma unroll
        for (int n = 0; n < 16; ++n) {             // N = 256 = 16 * 16
            bf16x8 b = bp[n * 64];
            acc[n] = __builtin_amdgcn_mfma_f32_16x16x32_bf16(a, b, acc[n], 0, 0, 0);
        }
    }

    // C layout: col = n*16 + (lane&15), row = (lane>>4)*4 + j
    #pragma unroll
    for (int n = 0; n < 16; ++n) {
        const int col = n * 16 + lr;
        #pragma unroll
        for (int j = 0; j < 4; ++j)
            Z[(v0 + lg * 4 + j) * 256 + col] = (__bf16)acc[n][j];
    }
}

// ---- edge apply: out[e][o] = sigmoid( Z[src][o] + Z[dst][128+o] ) ----
// 8 lanes per edge-slot, 2 edges per thread (e and e+32) -> 4 independent
// 16B gathers in flight per thread. 600000 / 64 edges-per-block = 9375 exact.
__launch_bounds__(256)
__global__ void edge_apply(const __bf16* __restrict__ Z,
                           const int* __restrict__ src_idx,
                           const int* __restrict__ dst_idx,
                           float* __restrict__ out) {
    const int slot = threadIdx.x >> 3;         // 0..31
    const int sub  = threadIdx.x & 7;
    const int e0   = blockIdx.x * 64 + slot;
    const int e1   = e0 + 32;

    const int sv0 = __builtin_nontemporal_load(src_idx + e0);
    const int dv0 = __builtin_nontemporal_load(dst_idx + e0);
    const int sv1 = __builtin_nontemporal_load(src_idx + e1);
    const int dv1 = __builtin_nontemporal_load(dst_idx + e1);

    if (sub == 0) {
        out[ALPHA_OFF + e0] = 1.0f;   // softmax over size-1 axis == 1
        out[ALPHA_OFF + e1] = 1.0f;
    }

    // issue all 8 gather loads before any compute (independent streams)
    const __bf16* zs0 = Z + sv0 * 256 + sub * 16;
    const __bf16* zd0 = Z + dv0 * 256 + 128 + sub * 16;
    const __bf16* zs1 = Z + sv1 * 256 + sub * 16;
    const __bf16* zd1 = Z + dv1 * 256 + 128 + sub * 16;
    bf16x8 s00 = *(const bf16x8*)(zs0);
    bf16x8 s01 = *(const bf16x8*)(zs0 + 8);
    bf16x8 d00 = *(const bf16x8*)(zd0);
    bf16x8 d01 = *(const bf16x8*)(zd0 + 8);
    bf16x8 s10 = *(const bf16x8*)(zs1);
    bf16x8 s11 = *(const bf16x8*)(zs1 + 8);
    bf16x8 d10 = *(const bf16x8*)(zd1);
    bf16x8 d11 = *(const bf16x8*)(zd1 + 8);

    float r0[16], r1[16];
    #pragma unroll
    for (int j = 0; j < 8; ++j) {
        float x00 = (float)s00[j] + (float)d00[j];
        float x01 = (float)s01[j] + (float)d01[j];
        float x10 = (float)s10[j] + (float)d10[j];
        float x11 = (float)s11[j] + (float)d11[j];
        r0[j]     = __builtin_amdgcn_rcpf(1.0f + __expf(-x00));
        r0[8 + j] = __builtin_amdgcn_rcpf(1.0f + __expf(-x01));
        r1[j]     = __builtin_amdgcn_rcpf(1.0f + __expf(-x10));
        r1[8 + j] = __builtin_amdgcn_rcpf(1.0f + __expf(-x11));
    }
    // each lane fills a contiguous 64B line; L2 write-combines the 4x16B
    f32x4* o0 = (f32x4*)(out + e0 * OUT_FEAT + sub * 16);
    f32x4* o1 = (f32x4*)(out + e1 * OUT_FEAT + sub * 16);
    #pragma unroll
    for (int q = 0; q < 4; ++q)
        o0[q] = (f32x4){r0[q * 4], r0[q * 4 + 1], r0[q * 4 + 2], r0[q * 4 + 3]};
    #pragma unroll
    for (int q = 0; q < 4; ++q)
        o1[q] = (f32x4){r1[q * 4], r1[q * 4 + 1], r1[q * 4 + 2], r1[q * 4 + 3]};
}

// ================= FALLBACK PATH (R3, needs only 64 KB ws) =================
__global__ void convert_w_fb(const float* __restrict__ W, __bf16* __restrict__ wl) {
    int gid = blockIdx.x * 256 + threadIdx.x;
    int lane = gid & 63;
    int nk   = gid >> 6;
    int n    = nk & 7;
    int kk   = nk >> 3;
    int row  = n * 16 + (lane & 15);
    int col  = kk * 32 + (lane >> 4) * 8;
    const float* src = W + row * IN_FEAT + col;
    bf16x8 h;
    #pragma unroll
    for (int j = 0; j < 8; ++j) h[j] = (__bf16)src[j];
    *(bf16x8*)(wl + gid * 8) = h;
}

__launch_bounds__(64, 2)
__global__ void edge_kernel_fb(const float* __restrict__ n_f,
                               const __bf16* __restrict__ wl,
                               const int*   __restrict__ src_idx,
                               const int*   __restrict__ dst_idx,
                               float* __restrict__ out) {
    const int lane = threadIdx.x;
    const int e0   = blockIdx.x * 64;
    const int lr   = lane & 15;
    const int lg   = lane >> 4;

    out[ALPHA_OFF + e0 + lane] = 1.0f;

    int sn[4], dn[4];
    #pragma unroll
    for (int r = 0; r < 4; ++r) {
        const int e = e0 + r * 16 + lr;
        sn[r] = src_idx[e];
        dn[r] = dst_idx[e];
    }
    f32x4 acc[4][8];
    #pragma unroll
    for (int r = 0; r < 4; ++r)
        #pragma unroll
        for (int n = 0; n < 8; ++n) acc[r][n] = (f32x4){0.f, 0.f, 0.f, 0.f};

    #pragma unroll
    for (int kk = 0; kk < 8; ++kk) {
        bf16x8 a[4];
        #pragma unroll
        for (int r = 0; r < 4; ++r) {
            const int node = (kk < 4) ? sn[r] : dn[r];
            const float* ap = n_f + node * D_NODE + (kk & 3) * 32 + lg * 8;
            float4 u0 = *(const float4*)ap;
            float4 u1 = *(const float4*)(ap + 4);
            a[r][0] = (__bf16)u0.x; a[r][1] = (__bf16)u0.y;
            a[r][2] = (__bf16)u0.z; a[r][3] = (__bf16)u0.w;
            a[r][4] = (__bf16)u1.x; a[r][5] = (__bf16)u1.y;
            a[r][6] = (__bf16)u1.z; a[r][7] = (__bf16)u1.w;
        }
        const bf16x8* bp = (const bf16x8*)(wl) + kk * 8 * 64 + lane;
        #pragma unroll
        for (int n = 0; n < 8; ++n) {
            bf16x8 b = bp[n * 64];
            #pragma unroll
            for (int r = 0; r < 4; ++r)
                acc[r][n] = __builtin_amdgcn_mfma_f32_16x16x32_bf16(a[r], b, acc[r][n], 0, 0, 0);
        }
    }
    #pragma unroll
    for (int r = 0; r < 4; ++r) {
        const int ebase = e0 + r * 16 + lg * 4;
        #pragma unroll
        for (int n = 0; n < 8; ++n) {
            const int col = n * 16 + lr;
            #pragma unroll
            for (int j = 0; j < 4; ++j) {
                float x = acc[r][n][j];
                out[(ebase + j) * OUT_FEAT + col] = __builtin_amdgcn_rcpf(1.0f + __expf(-x));
            }
        }
    }
}

extern "C" void kernel_launch(void* const* d_in, const int* in_sizes, int n_in,
                              void* d_out, int out_size, void* d_ws, size_t ws_size,
                              hipStream_t stream) {
    const float* n_f    = (const float*)d_in[0];
    const float* W_edge = (const float*)d_in[1];
    // d_in[2] = W_attn: mathematically dead (softmax over size-1 axis == 1)
    const int* src_idx  = (const int*)d_in[3];
    const int* dst_idx  = (const int*)d_in[4];
    float* out = (float*)d_out;

    const size_t need = 65536 + (size_t)N_NODES * 256 * sizeof(__bf16);  // wl + Z
    if (ws_size >= need) {
        __bf16* wl = (__bf16*)d_ws;                       // 64 KB
        __bf16* Z  = (__bf16*)((char*)d_ws + 65536);      // 25.6 MB
        convert_wcat<<<16, 256, 0, stream>>>(W_edge, wl);
        zgemm<<<N_NODES / 16, 64, 0, stream>>>(n_f, wl, Z);
        edge_apply<<<E_TOTAL / 64, 256, 0, stream>>>(Z, src_idx, dst_idx, out);
    } else {
        __bf16* wl = (__bf16*)d_ws;                       // 64 KB
        convert_w_fb<<<16, 256, 0, stream>>>(W_edge, wl);
        edge_kernel_fb<<<E_TOTAL / 64, 64, 0, stream>>>(n_f, wl, src_idx, dst_idx, out);
    }
}

// Round 8
// 126.866 us; speedup vs baseline: 1.7243x; 1.1102x over previous
//
#include <hip/hip_runtime.h>
#include <hip/hip_bf16.h>

// Problem constants (fixed by setup_inputs)
#define N_NODES  50000
#define D_NODE   128
#define E_TOTAL  600000
#define IN_FEAT  256      // 2 * d_node
#define OUT_FEAT 128
#define ALPHA_OFF (600000 * 128)   // fits in int32 (77.4M)

typedef __bf16 bf16x8 __attribute__((ext_vector_type(8)));
typedef __bf16 bf16x4 __attribute__((ext_vector_type(4)));
typedef float  f32x4  __attribute__((ext_vector_type(4)));

// ================= FAST PATH =================
// sigmoid(W.[nf_src|nf_dst]) = sigmoid(zs[src] + zd[dst]),
//   zs = n_f @ W[:, :128]^T,  zd = n_f @ W[:, 128:]^T  (per-node, reused ~12x/node)
// Z stored bf16 [N_NODES][256] (zs cols 0..127, zd cols 128..255) = 25.6 MB.
// R6 lesson: nt stores kill L2 write-combining (WRITE_SIZE 302->513 MB). Never.
// R8: 32 lanes/edge -> one f32x4 store/thread (wave store = 1KB contiguous),
// 8x the waves (300k) so TLP hides gather latency; full occupancy.

// ---- prep: Wcat -> per-fragment-swizzled bf16 (for the node-projection GEMM) ----
// Wcat[o2][k2] = o2<128 ? W[o2][k2] : W[o2-128][128+k2]   (o2<256, k2<128)
// wl[(((kk*16 + n)*64) + lane)*8 + j] = Wcat[n*16 + (lane&15)][kk*32 + (lane>>4)*8 + j]
__global__ void convert_wcat(const float* __restrict__ W, __bf16* __restrict__ wl) {
    int gid  = blockIdx.x * 256 + threadIdx.x;   // 0..4095, one bf16x8 each
    int lane = gid & 63;
    int nk   = gid >> 6;        // 0..63
    int n    = nk & 15;         // 16 col-groups (N=256)
    int kk   = nk >> 4;         // 0..3       (K=128)
    int o2   = n * 16 + (lane & 15);
    int k2   = kk * 32 + (lane >> 4) * 8;
    const float* src = (o2 < 128) ? (W + o2 * IN_FEAT + k2)
                                  : (W + (o2 - 128) * IN_FEAT + 128 + k2);
    bf16x8 h;
    #pragma unroll
    for (int j = 0; j < 8; ++j) h[j] = (__bf16)src[j];
    *(bf16x8*)(wl + gid * 8) = h;
}

// ---- node projection: Z[v][o2] = sum_k n_f[v][k] * Wcat[o2][k] ----
// one wave = 16 nodes x 256 cols, K=128. 50000 = 3125 * 16 exact.
__launch_bounds__(64)
__global__ void zgemm(const float* __restrict__ n_f,
                      const __bf16* __restrict__ wl,
                      __bf16* __restrict__ Z) {
    const int lane = threadIdx.x;
    const int v0   = blockIdx.x * 16;
    const int lr   = lane & 15;
    const int lg   = lane >> 4;

    f32x4 acc[16];
    #pragma unroll
    for (int n = 0; n < 16; ++n) acc[n] = (f32x4){0.f, 0.f, 0.f, 0.f};

    #pragma unroll
    for (int kk = 0; kk < 4; ++kk) {               // K = 128 = 4 * 32
        const float* ap = n_f + (v0 + lr) * D_NODE + kk * 32 + lg * 8;
        float4 v0f = *(const float4*)ap;
        float4 v1f = *(const float4*)(ap + 4);
        bf16x8 a;
        a[0] = (__bf16)v0f.x; a[1] = (__bf16)v0f.y;
        a[2] = (__bf16)v0f.z; a[3] = (__bf16)v0f.w;
        a[4] = (__bf16)v1f.x; a[5] = (__bf16)v1f.y;
        a[6] = (__bf16)v1f.z; a[7] = (__bf16)v1f.w;
        const bf16x8* bp = (const bf16x8*)(wl) + kk * 16 * 64 + lane;
        #pragma unroll
        for (int n = 0; n < 16; ++n) {             // N = 256 = 16 * 16
            bf16x8 b = bp[n * 64];
            acc[n] = __builtin_amdgcn_mfma_f32_16x16x32_bf16(a, b, acc[n], 0, 0, 0);
        }
    }

    // C layout: col = n*16 + (lane&15), row = (lane>>4)*4 + j
    #pragma unroll
    for (int n = 0; n < 16; ++n) {
        const int col = n * 16 + lr;
        #pragma unroll
        for (int j = 0; j < 4; ++j)
            Z[(v0 + lg * 4 + j) * 256 + col] = (__bf16)acc[n][j];
    }
}

// ---- edge apply: out[e][o] = sigmoid( Z[src][o] + Z[dst][128+o] ) ----
// 32 lanes per edge, 4 cols per thread. Wave store = 2 full edge rows = 1KB
// contiguous in ONE instruction. 600000*32/256 = 75000 blocks exact.
__launch_bounds__(256)
__global__ void edge_apply(const __bf16* __restrict__ Z,
                           const int* __restrict__ src_idx,
                           const int* __restrict__ dst_idx,
                           float* __restrict__ out) {
    const int t  = blockIdx.x * 256 + threadIdx.x;
    const int e  = t >> 5;             // 32 lanes per edge
    const int c4 = (t & 31) * 4;       // col group (0,4,...,124)

    const int sv = src_idx[e];         // L1-broadcast across the 32 lanes
    const int dv = dst_idx[e];

    if ((t & 31) == 0) out[ALPHA_OFF + e] = 1.0f;  // softmax(size-1) == 1

    bf16x4 zs = *(const bf16x4*)(Z + sv * 256 + c4);
    bf16x4 zd = *(const bf16x4*)(Z + dv * 256 + 128 + c4);

    f32x4 r;
    #pragma unroll
    for (int j = 0; j < 4; ++j) {
        float x = (float)zs[j] + (float)zd[j];
        r[j] = __builtin_amdgcn_rcpf(1.0f + __expf(-x));
    }
    *(f32x4*)(out + e * OUT_FEAT + c4) = r;
}

// ================= FALLBACK PATH (R3, needs only 64 KB ws) =================
__global__ void convert_w_fb(const float* __restrict__ W, __bf16* __restrict__ wl) {
    int gid = blockIdx.x * 256 + threadIdx.x;
    int lane = gid & 63;
    int nk   = gid >> 6;
    int n    = nk & 7;
    int kk   = nk >> 3;
    int row  = n * 16 + (lane & 15);
    int col  = kk * 32 + (lane >> 4) * 8;
    const float* src = W + row * IN_FEAT + col;
    bf16x8 h;
    #pragma unroll
    for (int j = 0; j < 8; ++j) h[j] = (__bf16)src[j];
    *(bf16x8*)(wl + gid * 8) = h;
}

__launch_bounds__(64, 2)
__global__ void edge_kernel_fb(const float* __restrict__ n_f,
                               const __bf16* __restrict__ wl,
                               const int*   __restrict__ src_idx,
                               const int*   __restrict__ dst_idx,
                               float* __restrict__ out) {
    const int lane = threadIdx.x;
    const int e0   = blockIdx.x * 64;
    const int lr   = lane & 15;
    const int lg   = lane >> 4;

    out[ALPHA_OFF + e0 + lane] = 1.0f;

    int sn[4], dn[4];
    #pragma unroll
    for (int r = 0; r < 4; ++r) {
        const int e = e0 + r * 16 + lr;
        sn[r] = src_idx[e];
        dn[r] = dst_idx[e];
    }
    f32x4 acc[4][8];
    #pragma unroll
    for (int r = 0; r < 4; ++r)
        #pragma unroll
        for (int n = 0; n < 8; ++n) acc[r][n] = (f32x4){0.f, 0.f, 0.f, 0.f};

    #pragma unroll
    for (int kk = 0; kk < 8; ++kk) {
        bf16x8 a[4];
        #pragma unroll
        for (int r = 0; r < 4; ++r) {
            const int node = (kk < 4) ? sn[r] : dn[r];
            const float* ap = n_f + node * D_NODE + (kk & 3) * 32 + lg * 8;
            float4 u0 = *(const float4*)ap;
            float4 u1 = *(const float4*)(ap + 4);
            a[r][0] = (__bf16)u0.x; a[r][1] = (__bf16)u0.y;
            a[r][2] = (__bf16)u0.z; a[r][3] = (__bf16)u0.w;
            a[r][4] = (__bf16)u1.x; a[r][5] = (__bf16)u1.y;
            a[r][6] = (__bf16)u1.z; a[r][7] = (__bf16)u1.w;
        }
        const bf16x8* bp = (const bf16x8*)(wl) + kk * 8 * 64 + lane;
        #pragma unroll
        for (int n = 0; n < 8; ++n) {
            bf16x8 b = bp[n * 64];
            #pragma unroll
            for (int r = 0; r < 4; ++r)
                acc[r][n] = __builtin_amdgcn_mfma_f32_16x16x32_bf16(a[r], b, acc[r][n], 0, 0, 0);
        }
    }
    #pragma unroll
    for (int r = 0; r < 4; ++r) {
        const int ebase = e0 + r * 16 + lg * 4;
        #pragma unroll
        for (int n = 0; n < 8; ++n) {
            const int col = n * 16 + lr;
            #pragma unroll
            for (int j = 0; j < 4; ++j) {
                float x = acc[r][n][j];
                out[(ebase + j) * OUT_FEAT + col] = __builtin_amdgcn_rcpf(1.0f + __expf(-x));
            }
        }
    }
}

extern "C" void kernel_launch(void* const* d_in, const int* in_sizes, int n_in,
                              void* d_out, int out_size, void* d_ws, size_t ws_size,
                              hipStream_t stream) {
    const float* n_f    = (const float*)d_in[0];
    const float* W_edge = (const float*)d_in[1];
    // d_in[2] = W_attn: mathematically dead (softmax over size-1 axis == 1)
    const int* src_idx  = (const int*)d_in[3];
    const int* dst_idx  = (const int*)d_in[4];
    float* out = (float*)d_out;

    const size_t need = 65536 + (size_t)N_NODES * 256 * sizeof(__bf16);  // wl + Z
    if (ws_size >= need) {
        __bf16* wl = (__bf16*)d_ws;                       // 64 KB
        __bf16* Z  = (__bf16*)((char*)d_ws + 65536);      // 25.6 MB
        convert_wcat<<<16, 256, 0, stream>>>(W_edge, wl);
        zgemm<<<N_NODES / 16, 64, 0, stream>>>(n_f, wl, Z);
        edge_apply<<<(E_TOTAL * 32) / 256, 256, 0, stream>>>(Z, src_idx, dst_idx, out);
    } else {
        __bf16* wl = (__bf16*)d_ws;                       // 64 KB
        convert_w_fb<<<16, 256, 0, stream>>>(W_edge, wl);
        edge_kernel_fb<<<E_TOTAL / 64, 64, 0, stream>>>(n_f, wl, src_idx, dst_idx, out);
    }
}

// Round 9
// 109.316 us; speedup vs baseline: 2.0012x; 1.1605x over previous
//
#include <hip/hip_runtime.h>
#include <hip/hip_bf16.h>

// Problem constants (fixed by setup_inputs)
#define N_NODES  50000
#define D_NODE   128
#define E_TOTAL  600000
#define IN_FEAT  256      // 2 * d_node
#define OUT_FEAT 128
#define ALPHA_OFF (600000 * 128)   // fits in int32 (77.4M)

typedef __bf16 bf16x8 __attribute__((ext_vector_type(8)));
typedef __bf16 bf16x4 __attribute__((ext_vector_type(4)));
typedef float  f32x4  __attribute__((ext_vector_type(4)));

// ================= FAST PATH =================
// sigmoid(W.[nf_src|nf_dst]) = sigmoid(zs[src] + zd[dst]),
//   zs = n_f @ W[:, :128]^T,  zd = n_f @ W[:, 128:]^T  (per-node, reused ~12x/node)
// Z stored bf16 [N_NODES][256] (zs cols 0..127, zd cols 128..255) = 25.6 MB.
// R6 lesson: nt on PARTIAL-LINE stores kills write-combining (1.7x WRITE amp).
// R9: retry nt now that each wave's store is 1KB contiguous in ONE instruction
// (full 128B lines) -> stream writes bypass L2/L3 without evicting Z.

// ---- prep: Wcat -> per-fragment-swizzled bf16 (for the node-projection GEMM) ----
// Wcat[o2][k2] = o2<128 ? W[o2][k2] : W[o2-128][128+k2]   (o2<256, k2<128)
// wl[(((kk*16 + n)*64) + lane)*8 + j] = Wcat[n*16 + (lane&15)][kk*32 + (lane>>4)*8 + j]
__global__ void convert_wcat(const float* __restrict__ W, __bf16* __restrict__ wl) {
    int gid  = blockIdx.x * 256 + threadIdx.x;   // 0..4095, one bf16x8 each
    int lane = gid & 63;
    int nk   = gid >> 6;        // 0..63
    int n    = nk & 15;         // 16 col-groups (N=256)
    int kk   = nk >> 4;         // 0..3       (K=128)
    int o2   = n * 16 + (lane & 15);
    int k2   = kk * 32 + (lane >> 4) * 8;
    const float* src = (o2 < 128) ? (W + o2 * IN_FEAT + k2)
                                  : (W + (o2 - 128) * IN_FEAT + 128 + k2);
    bf16x8 h;
    #pragma unroll
    for (int j = 0; j < 8; ++j) h[j] = (__bf16)src[j];
    *(bf16x8*)(wl + gid * 8) = h;
}

// ---- node projection: Z[v][o2] = sum_k n_f[v][k] * Wcat[o2][k] ----
// one wave = 16 nodes x 256 cols, K=128. 50000 = 3125 * 16 exact.
__launch_bounds__(64)
__global__ void zgemm(const float* __restrict__ n_f,
                      const __bf16* __restrict__ wl,
                      __bf16* __restrict__ Z) {
    const int lane = threadIdx.x;
    const int v0   = blockIdx.x * 16;
    const int lr   = lane & 15;
    const int lg   = lane >> 4;

    f32x4 acc[16];
    #pragma unroll
    for (int n = 0; n < 16; ++n) acc[n] = (f32x4){0.f, 0.f, 0.f, 0.f};

    #pragma unroll
    for (int kk = 0; kk < 4; ++kk) {               // K = 128 = 4 * 32
        const float* ap = n_f + (v0 + lr) * D_NODE + kk * 32 + lg * 8;
        float4 v0f = *(const float4*)ap;
        float4 v1f = *(const float4*)(ap + 4);
        bf16x8 a;
        a[0] = (__bf16)v0f.x; a[1] = (__bf16)v0f.y;
        a[2] = (__bf16)v0f.z; a[3] = (__bf16)v0f.w;
        a[4] = (__bf16)v1f.x; a[5] = (__bf16)v1f.y;
        a[6] = (__bf16)v1f.z; a[7] = (__bf16)v1f.w;
        const bf16x8* bp = (const bf16x8*)(wl) + kk * 16 * 64 + lane;
        #pragma unroll
        for (int n = 0; n < 16; ++n) {             // N = 256 = 16 * 16
            bf16x8 b = bp[n * 64];
            acc[n] = __builtin_amdgcn_mfma_f32_16x16x32_bf16(a, b, acc[n], 0, 0, 0);
        }
    }

    // C layout: col = n*16 + (lane&15), row = (lane>>4)*4 + j
    #pragma unroll
    for (int n = 0; n < 16; ++n) {
        const int col = n * 16 + lr;
        #pragma unroll
        for (int j = 0; j < 4; ++j)
            Z[(v0 + lg * 4 + j) * 256 + col] = (__bf16)acc[n][j];
    }
}

// ---- edge apply: out[e][o] = sigmoid( Z[src][o] + Z[dst][128+o] ) ----
// 32 lanes per edge, 4 cols per thread. Wave store = 1KB contiguous in ONE
// nt instruction (full lines -> no write amp, no L3 pollution).
__launch_bounds__(256)
__global__ void edge_apply(const __bf16* __restrict__ Z,
                           const int* __restrict__ src_idx,
                           const int* __restrict__ dst_idx,
                           float* __restrict__ out) {
    const int t  = blockIdx.x * 256 + threadIdx.x;
    const int e  = t >> 5;             // 32 lanes per edge
    const int c4 = (t & 31) * 4;       // col group (0,4,...,124)

    const int sv = src_idx[e];         // L1-broadcast across the 32 lanes
    const int dv = dst_idx[e];

    if ((t & 31) == 0) out[ALPHA_OFF + e] = 1.0f;  // softmax(size-1) == 1

    bf16x4 zs = *(const bf16x4*)(Z + sv * 256 + c4);
    bf16x4 zd = *(const bf16x4*)(Z + dv * 256 + 128 + c4);

    f32x4 r;
    #pragma unroll
    for (int j = 0; j < 4; ++j) {
        float x = (float)zs[j] + (float)zd[j];
        r[j] = __builtin_amdgcn_rcpf(1.0f + __expf(-x));
    }
    __builtin_nontemporal_store(r, (f32x4*)(out + e * OUT_FEAT + c4));
}

// ================= FALLBACK PATH (R3, needs only 64 KB ws) =================
__global__ void convert_w_fb(const float* __restrict__ W, __bf16* __restrict__ wl) {
    int gid = blockIdx.x * 256 + threadIdx.x;
    int lane = gid & 63;
    int nk   = gid >> 6;
    int n    = nk & 7;
    int kk   = nk >> 3;
    int row  = n * 16 + (lane & 15);
    int col  = kk * 32 + (lane >> 4) * 8;
    const float* src = W + row * IN_FEAT + col;
    bf16x8 h;
    #pragma unroll
    for (int j = 0; j < 8; ++j) h[j] = (__bf16)src[j];
    *(bf16x8*)(wl + gid * 8) = h;
}

__launch_bounds__(64, 2)
__global__ void edge_kernel_fb(const float* __restrict__ n_f,
                               const __bf16* __restrict__ wl,
                               const int*   __restrict__ src_idx,
                               const int*   __restrict__ dst_idx,
                               float* __restrict__ out) {
    const int lane = threadIdx.x;
    const int e0   = blockIdx.x * 64;
    const int lr   = lane & 15;
    const int lg   = lane >> 4;

    out[ALPHA_OFF + e0 + lane] = 1.0f;

    int sn[4], dn[4];
    #pragma unroll
    for (int r = 0; r < 4; ++r) {
        const int e = e0 + r * 16 + lr;
        sn[r] = src_idx[e];
        dn[r] = dst_idx[e];
    }
    f32x4 acc[4][8];
    #pragma unroll
    for (int r = 0; r < 4; ++r)
        #pragma unroll
        for (int n = 0; n < 8; ++n) acc[r][n] = (f32x4){0.f, 0.f, 0.f, 0.f};

    #pragma unroll
    for (int kk = 0; kk < 8; ++kk) {
        bf16x8 a[4];
        #pragma unroll
        for (int r = 0; r < 4; ++r) {
            const int node = (kk < 4) ? sn[r] : dn[r];
            const float* ap = n_f + node * D_NODE + (kk & 3) * 32 + lg * 8;
            float4 u0 = *(const float4*)ap;
            float4 u1 = *(const float4*)(ap + 4);
            a[r][0] = (__bf16)u0.x; a[r][1] = (__bf16)u0.y;
            a[r][2] = (__bf16)u0.z; a[r][3] = (__bf16)u0.w;
            a[r][4] = (__bf16)u1.x; a[r][5] = (__bf16)u1.y;
            a[r][6] = (__bf16)u1.z; a[r][7] = (__bf16)u1.w;
        }
        const bf16x8* bp = (const bf16x8*)(wl) + kk * 8 * 64 + lane;
        #pragma unroll
        for (int n = 0; n < 8; ++n) {
            bf16x8 b = bp[n * 64];
            #pragma unroll
            for (int r = 0; r < 4; ++r)
                acc[r][n] = __builtin_amdgcn_mfma_f32_16x16x32_bf16(a[r], b, acc[r][n], 0, 0, 0);
        }
    }
    #pragma unroll
    for (int r = 0; r < 4; ++r) {
        const int ebase = e0 + r * 16 + lg * 4;
        #pragma unroll
        for (int n = 0; n < 8; ++n) {
            const int col = n * 16 + lr;
            #pragma unroll
            for (int j = 0; j < 4; ++j) {
                float x = acc[r][n][j];
                out[(ebase + j) * OUT_FEAT + col] = __builtin_amdgcn_rcpf(1.0f + __expf(-x));
            }
        }
    }
}

extern "C" void kernel_launch(void* const* d_in, const int* in_sizes, int n_in,
                              void* d_out, int out_size, void* d_ws, size_t ws_size,
                              hipStream_t stream) {
    const float* n_f    = (const float*)d_in[0];
    const float* W_edge = (const float*)d_in[1];
    // d_in[2] = W_attn: mathematically dead (softmax over size-1 axis == 1)
    const int* src_idx  = (const int*)d_in[3];
    const int* dst_idx  = (const int*)d_in[4];
    float* out = (float*)d_out;

    const size_t need = 65536 + (size_t)N_NODES * 256 * sizeof(__bf16);  // wl + Z
    if (ws_size >= need) {
        __bf16* wl = (__bf16*)d_ws;                       // 64 KB
        __bf16* Z  = (__bf16*)((char*)d_ws + 65536);      // 25.6 MB
        convert_wcat<<<16, 256, 0, stream>>>(W_edge, wl);
        zgemm<<<N_NODES / 16, 64, 0, stream>>>(n_f, wl, Z);
        edge_apply<<<(E_TOTAL * 32) / 256, 256, 0, stream>>>(Z, src_idx, dst_idx, out);
    } else {
        __bf16* wl = (__bf16*)d_ws;                       // 64 KB
        convert_w_fb<<<16, 256, 0, stream>>>(W_edge, wl);
        edge_kernel_fb<<<E_TOTAL / 64, 64, 0, stream>>>(n_f, wl, src_idx, dst_idx, out);
    }
}